// Round 1
// baseline (4069.884 us; speedup 1.0000x reference)
//
#include <hip/hip_runtime.h>
#include <hip/hip_bf16.h>

// ---------------------------------------------------------------------------
// SAGE layer:
//   acc_v[n] = sum_{e: v[e]==n} efeats[e];  deg_v[n] = count   (same for u)
//   cat[n]   = [acc_v/max(deg_v,1), acc_u/max(deg_u,1)]        (128)
//   h[n]     = relu(Wn @ cat[n] + bn)                           (64)
//   g[n]     = We[:, :64] @ h[n] + be                           (64, precomputed)
//   edge[e]  = g[u[e]] + We[:, 64:] @ efeats[e]                 (64)
// Output: [h (N*64) | edge (E*64)] f32.
// ---------------------------------------------------------------------------

__global__ __launch_bounds__(256) void scatter_kernel(
    const float* __restrict__ ef, const int* __restrict__ u, const int* __restrict__ v,
    float* __restrict__ acc_u, float* __restrict__ acc_v,
    float* __restrict__ deg_u, float* __restrict__ deg_v, int E)
{
    int t = blockIdx.x * blockDim.x + threadIdx.x;
    int e = t >> 4;              // 16 threads per edge, float4 each
    if (e >= E) return;
    int q = (t & 15) * 4;
    float4 f = *reinterpret_cast<const float4*>(ef + (size_t)e * 64 + q);
    int uu = u[e], vv = v[e];
    float* av = acc_v + (size_t)vv * 64 + q;
    float* au = acc_u + (size_t)uu * 64 + q;
    unsafeAtomicAdd(av + 0, f.x);
    unsafeAtomicAdd(av + 1, f.y);
    unsafeAtomicAdd(av + 2, f.z);
    unsafeAtomicAdd(av + 3, f.w);
    unsafeAtomicAdd(au + 0, f.x);
    unsafeAtomicAdd(au + 1, f.y);
    unsafeAtomicAdd(au + 2, f.z);
    unsafeAtomicAdd(au + 3, f.w);
    if (q == 0) {
        unsafeAtomicAdd(deg_v + vv, 1.0f);
        unsafeAtomicAdd(deg_u + uu, 1.0f);
    }
}

__global__ __launch_bounds__(256) void node_kernel(
    const float* __restrict__ acc_u, const float* __restrict__ acc_v,
    const float* __restrict__ deg_u, const float* __restrict__ deg_v,
    const float* __restrict__ Wn, const float* __restrict__ bn,
    const float* __restrict__ We, const float* __restrict__ be,
    float* __restrict__ h_out, float* __restrict__ g, int N)
{
    // WnT[d][o] = Wn[o][d] (pad 65 -> conflict-free lane-indexed reads)
    __shared__ float WnT[128][65];
    __shared__ float WeLT[64][65];
    __shared__ float cat[4][128];   // per-wave row; no cross-wave sharing
    __shared__ float h_lds[4][64];

    for (int i = threadIdx.x; i < 64 * 128; i += 256) {
        int o = i >> 7, d = i & 127;
        WnT[d][o] = Wn[i];
    }
    for (int i = threadIdx.x; i < 64 * 64; i += 256) {
        int o = i >> 6, k = i & 63;
        WeLT[k][o] = We[o * 128 + k];     // left half of We
    }
    __syncthreads();

    int w = threadIdx.x >> 6;
    int lane = threadIdx.x & 63;
    float bnv = bn[lane];
    float bev = be[lane];

    for (int n0 = blockIdx.x * 4; n0 < N; n0 += gridDim.x * 4) {
        int n = n0 + w;                 // each wave owns one node; no barriers needed
        if (n >= N) continue;
        float dv = fmaxf(deg_v[n], 1.0f);
        float du = fmaxf(deg_u[n], 1.0f);
        cat[w][lane]      = acc_v[(size_t)n * 64 + lane] / dv;
        cat[w][64 + lane] = acc_u[(size_t)n * 64 + lane] / du;

        float s = bnv;
        #pragma unroll
        for (int d4 = 0; d4 < 32; d4++) {
            float4 c = *reinterpret_cast<const float4*>(&cat[w][d4 * 4]);  // broadcast
            s += WnT[d4 * 4 + 0][lane] * c.x;
            s += WnT[d4 * 4 + 1][lane] * c.y;
            s += WnT[d4 * 4 + 2][lane] * c.z;
            s += WnT[d4 * 4 + 3][lane] * c.w;
        }
        s = fmaxf(s, 0.0f);
        h_out[(size_t)n * 64 + lane] = s;
        h_lds[w][lane] = s;

        float sg = bev;
        #pragma unroll
        for (int k4 = 0; k4 < 16; k4++) {
            float4 hh = *reinterpret_cast<const float4*>(&h_lds[w][k4 * 4]); // broadcast
            sg += WeLT[k4 * 4 + 0][lane] * hh.x;
            sg += WeLT[k4 * 4 + 1][lane] * hh.y;
            sg += WeLT[k4 * 4 + 2][lane] * hh.z;
            sg += WeLT[k4 * 4 + 3][lane] * hh.w;
        }
        g[(size_t)n * 64 + lane] = sg;
    }
}

__global__ __launch_bounds__(256) void edge_kernel(
    const float* __restrict__ ef, const int* __restrict__ u,
    const float* __restrict__ We, const float* __restrict__ g,
    float* __restrict__ out, int E)
{
    __shared__ float ef_lds[4][64];
    int w = threadIdx.x >> 6, lane = threadIdx.x & 63;

    // Each lane holds row `lane` of We_right (64 f32 = 16 float4 in VGPRs).
    float4 wr[16];
    #pragma unroll
    for (int i = 0; i < 16; i++)
        wr[i] = *reinterpret_cast<const float4*>(We + lane * 128 + 64 + i * 4);

    for (int e = blockIdx.x * 4 + w; e < E; e += gridDim.x * 4) {
        ef_lds[w][lane] = ef[(size_t)e * 64 + lane];   // 256B coalesced per wave
        int uu = u[e];
        float acc = g[(size_t)uu * 64 + lane];          // includes be
        #pragma unroll
        for (int i = 0; i < 16; i++) {
            float4 fv = *reinterpret_cast<const float4*>(&ef_lds[w][i * 4]); // broadcast
            acc += wr[i].x * fv.x + wr[i].y * fv.y + wr[i].z * fv.z + wr[i].w * fv.w;
        }
        out[(size_t)e * 64 + lane] = acc;
    }
}

extern "C" void kernel_launch(void* const* d_in, const int* in_sizes, int n_in,
                              void* d_out, int out_size, void* d_ws, size_t ws_size,
                              hipStream_t stream)
{
    // inputs: 0 nfeats (UNUSED by reference), 1 efeats, 2 u, 3 v, 4 Wn, 5 bn, 6 We, 7 be
    const float* efeats = (const float*)d_in[1];
    const int*   u      = (const int*)d_in[2];
    const int*   v      = (const int*)d_in[3];
    const float* Wn     = (const float*)d_in[4];
    const float* bn     = (const float*)d_in[5];
    const float* We     = (const float*)d_in[6];
    const float* be     = (const float*)d_in[7];

    const int N = in_sizes[0] / 64;
    const int E = in_sizes[2];

    float* h_out = (float*)d_out;
    float* e_out = h_out + (size_t)N * 64;

    // scratch: acc_v[N*64] acc_u[N*64] deg_v[N] deg_u[N] (memset 0) + g[N*64]
    size_t acc_floats = (size_t)N * 130;            // accs + degs
    size_t need = (acc_floats + (size_t)N * 64) * sizeof(float);

    float *acc_v, *acc_u, *deg_v, *deg_u, *g;
    if (ws_size >= need) {
        float* ws = (float*)d_ws;
        acc_v = ws;
        acc_u = acc_v + (size_t)N * 64;
        deg_v = acc_u + (size_t)N * 64;
        deg_u = deg_v + N;
        g     = deg_u + N;
    } else {
        // fall back: accs/degs live in the edge-output region (dead until edge_kernel
        // overwrites it); g (read during edge_kernel) lives in ws.
        acc_v = e_out;
        acc_u = acc_v + (size_t)N * 64;
        deg_v = acc_u + (size_t)N * 64;
        deg_u = deg_v + N;
        g     = (float*)d_ws;
    }

    hipMemsetAsync(acc_v, 0, acc_floats * sizeof(float), stream);

    int scatter_blocks = (int)(((size_t)E * 16 + 255) / 256);
    scatter_kernel<<<scatter_blocks, 256, 0, stream>>>(efeats, u, v, acc_u, acc_v, deg_u, deg_v, E);
    node_kernel<<<1024, 256, 0, stream>>>(acc_u, acc_v, deg_u, deg_v, Wn, bn, We, be, h_out, g, N);
    edge_kernel<<<2048, 256, 0, stream>>>(efeats, u, We, g, e_out, E);
}